// Round 6
// baseline (324.181 us; speedup 1.0000x reference)
//
#include <hip/hip_runtime.h>
#include <hip/hip_fp16.h>

// CommNet critic forward, fully fused: 1 workgroup = 2 batches (64 agent-rows).
// All GEMMs via v_mfma_f32_16x16x32_f16 (fp32 accumulate). B=2048,A=32,D=128,H=256.
// V7: wave tiling 64x16 -> 32x32 (2 row-halves x 8 col-groups; 2x2 MFMA tiles/wave).
//     LDS A-fragment ds_read_b128 per wave halves (144->72; ~26% of runtime was
//     LDS-pipe). B-frag global loads double but stay L2-resident (~19TB/s < 34 ceiling).
//     SA reverted to 264 and waves_per_eu dropped (both proven perf-neutral V5/V6).

#define NB   2048
#define NA   32
#define DIN  128
#define HID  256
#define SA   264   // f16 row stride for activation LDS tiles (528B stride -> 4-bank stagger)
#define MROWS 64   // 2 batches x 32 agents

typedef _Float16 half8  __attribute__((ext_vector_type(8)));
typedef float    float4v __attribute__((ext_vector_type(4)));

// f16 weight-fragment arena layout in d_ws (element offsets)
#define ENC_OFF    0
#define FOBS_OFF   32768
#define WIH_OFF    98304
#define WHH_OFF    294912
#define PREP_TOTAL 491520   // f16 elements -> 983040 bytes needed in ws

// Pre-arrange weights into exact MFMA B-fragment order, f16:
// frag[((ks*NT + nt)*64 + lane)*8 + j] = W[nt*16 + lane%16][ks*32 + (lane/16)*8 + j]
__global__ void prep_weights(const float* __restrict__ encW, const float* __restrict__ fobsW,
                             const float* __restrict__ wih,  const float* __restrict__ whh,
                             _Float16* __restrict__ prep) {
    int F = blockIdx.x * 256 + threadIdx.x;
    if (F >= PREP_TOTAL) return;
    const float* src; int K, NT, local = F;
    if (F < FOBS_OFF)     { src = encW;  K = 128; NT = 16; }
    else if (F < WIH_OFF) { src = fobsW; K = 256; NT = 16; local = F - FOBS_OFF; }
    else if (F < WHH_OFF) { src = wih;   K = 256; NT = 48; local = F - WIH_OFF; }
    else                  { src = whh;   K = 256; NT = 48; local = F - WHH_OFF; }
    int j    = local & 7;
    int lane = (local >> 3) & 63;
    int t    = local >> 9;
    int nt   = t % NT;
    int ks   = t / NT;
    int col  = nt * 16 + (lane & 15);
    int k    = ks * 32 + ((lane >> 4) << 3) + j;
    prep[F] = (_Float16)src[col * K + k];
}

__device__ __forceinline__ float sigmoid_f(float x) {
    x = fminf(fmaxf(x, -30.f), 30.f);
    return 1.f / (1.f + __expf(-x));
}
__device__ __forceinline__ float tanh_f(float x) {
    x = fminf(fmaxf(x, -15.f), 15.f);
    float e = __expf(-2.f * x);
    return (1.f - e) / (1.f + e);
}

__device__ __forceinline__ void zero22(float4v a[2][2]) {
    float4v z = {0.f, 0.f, 0.f, 0.f};
    a[0][0] = z; a[0][1] = z; a[1][0] = z; a[1][1] = z;
}

// Load one MFMA B-fragment (16 cols x 32 k) either from prepped arena or raw fp32.
__device__ __forceinline__ half8 ldB(const _Float16* __restrict__ prepm, int NT, int nt, int ks,
                                     const float* __restrict__ raw, int K, int use_prep, int lane) {
    if (use_prep)
        return *(const half8*)(prepm + (((ks * NT + nt) * 64 + lane) << 3));
    half8 b;
    int l16 = lane & 15, kq = (lane >> 4) << 3;
    #pragma unroll
    for (int j = 0; j < 8; j++)
        b[j] = (_Float16)raw[(nt * 16 + l16) * K + ks * 32 + kq + j];
    return b;
}

// One wave computes 32 rows x 32 cols: 2x2 MFMA tiles (mt 0..1, ntg0..ntg0+1).
// Abuf points at the wave's first row (rowB already applied).
template<int KSTEPS>
__device__ __forceinline__ void gemm_tile(const _Float16* __restrict__ Abuf,
        const _Float16* __restrict__ prepm, int NT, int ntg0,
        const float* __restrict__ raw, int K, int use_prep,
        int lane, float4v acc[2][2])
{
    const int l16 = lane & 15;
    const int kq  = (lane >> 4) << 3;
    #pragma unroll 2
    for (int ks = 0; ks < KSTEPS; ks++) {
        int kbase = ks * 32 + kq;
        half8 a0 = *(const half8*)(Abuf + l16 * SA + kbase);
        half8 a1 = *(const half8*)(Abuf + (16 + l16) * SA + kbase);
        half8 b0 = ldB(prepm, NT, ntg0,     ks, raw, K, use_prep, lane);
        half8 b1 = ldB(prepm, NT, ntg0 + 1, ks, raw, K, use_prep, lane);
        acc[0][0] = __builtin_amdgcn_mfma_f32_16x16x32_f16(a0, b0, acc[0][0], 0, 0, 0);
        acc[0][1] = __builtin_amdgcn_mfma_f32_16x16x32_f16(a0, b1, acc[0][1], 0, 0, 0);
        acc[1][0] = __builtin_amdgcn_mfma_f32_16x16x32_f16(a1, b0, acc[1][0], 0, 0, 0);
        acc[1][1] = __builtin_amdgcn_mfma_f32_16x16x32_f16(a1, b1, acc[1][1], 0, 0, 0);
    }
}

__global__ __launch_bounds__(1024) void commnet_fused(
    const float* __restrict__ obs, const _Float16* __restrict__ prep,
    const float* __restrict__ enc_b, const float* __restrict__ fobs_b,
    const float* __restrict__ b_ih, const float* __restrict__ b_hh,
    const float* __restrict__ dec_W, const float* __restrict__ dec_b,
    float* __restrict__ out,
    const float* __restrict__ encW, const float* __restrict__ fobsW,
    const float* __restrict__ wih, const float* __restrict__ whh,
    int use_prep)
{
    const int b    = blockIdx.x;       // block handles batches 2b, 2b+1 (rows 0..63)
    const int tid  = threadIdx.x;
    const int lane = tid & 63;
    const int w    = tid >> 6;         // wave 0..15
    const int wr   = w >> 3;           // row half: rows wr*32..wr*32+31 (== batch wr)
    const int wc   = w & 7;            // col group: cols wc*32..wc*32+31
    const int l16  = lane & 15;
    const int quad = lane >> 4;
    const int kq   = quad << 3;
    const int ntg0 = wc * 2;           // first 16-col tile index within 256
    const int rowB = wr * 32;

    __shared__ __align__(16) _Float16 sA[2][MROWS * SA];
    __shared__ __align__(16) float S[2][HID];   // per-batch column sums of h1
    __shared__ float Srow[MROWS];               // decoder row accumulators

    // ---- stage obs (fp32 global -> f16 LDS): 64 rows x 128, one half8 per thread
    {
        const float* obsb = obs + (size_t)b * MROWS * DIN;
        int r   = tid >> 4;            // 16 chunks per 128-wide row, 64 rows
        int off = (tid & 15) << 3;
        const float* src = obsb + r * DIN + off;
        float4v v0 = *(const float4v*)(src);
        float4v v1 = *(const float4v*)(src + 4);
        half8 hv;
        hv[0] = (_Float16)v0[0]; hv[1] = (_Float16)v0[1];
        hv[2] = (_Float16)v0[2]; hv[3] = (_Float16)v0[3];
        hv[4] = (_Float16)v1[0]; hv[5] = (_Float16)v1[1];
        hv[6] = (_Float16)v1[2]; hv[7] = (_Float16)v1[3];
        *(half8*)(&sA[0][r * SA + off]) = hv;
    }
    __syncthreads();

    float4v acc[2][2];

    // ---- encoder: e = relu(obs @ encW^T + enc_b) : T0 -> T1
    {
        zero22(acc);
        gemm_tile<4>(&sA[0][rowB * SA], prep + ENC_OFF, 16, ntg0, encW, DIN, use_prep, lane, acc);
        #pragma unroll
        for (int nt = 0; nt < 2; nt++) {
            int col = wc * 32 + nt * 16 + l16;
            float bb = enc_b[col];
            #pragma unroll
            for (int mt = 0; mt < 2; mt++)
                #pragma unroll
                for (int r = 0; r < 4; r++) {
                    int row = rowB + mt * 16 + quad * 4 + r;
                    sA[1][row * SA + col] = (_Float16)fmaxf(acc[mt][nt][r] + bb, 0.f);
                }
        }
    }
    __syncthreads();

    // ---- fobs: h = e @ fobsW^T + fobs_b : T1 -> T0
    {
        zero22(acc);
        gemm_tile<8>(&sA[1][rowB * SA], prep + FOBS_OFF, 16, ntg0, fobsW, HID, use_prep, lane, acc);
        #pragma unroll
        for (int nt = 0; nt < 2; nt++) {
            int col = wc * 32 + nt * 16 + l16;
            float bb = fobs_b[col];
            #pragma unroll
            for (int mt = 0; mt < 2; mt++)
                #pragma unroll
                for (int r = 0; r < 4; r++) {
                    int row = rowB + mt * 16 + quad * 4 + r;
                    sA[0][row * SA + col] = (_Float16)(acc[mt][nt][r] + bb);
                }
        }
    }
    __syncthreads();

    // ---- GRU1 fused (x=0 so gi = b_ih). A = T0 (h). One K-pass, 3 gate acc sets.
    {
        float4v aR[2][2], aZ[2][2], aN[2][2];
        zero22(aR); zero22(aZ); zero22(aN);
        #pragma unroll 2
        for (int ks = 0; ks < 8; ks++) {
            const int kbase = ks * 32 + kq;
            half8 a0 = *(const half8*)(&sA[0][(rowB + l16) * SA + kbase]);
            half8 a1 = *(const half8*)(&sA[0][(rowB + 16 + l16) * SA + kbase]);
            half8 bR0 = ldB(prep + WHH_OFF, 48,  0 + ntg0,     ks, whh, HID, use_prep, lane);
            half8 bR1 = ldB(prep + WHH_OFF, 48,  0 + ntg0 + 1, ks, whh, HID, use_prep, lane);
            aR[0][0] = __builtin_amdgcn_mfma_f32_16x16x32_f16(a0, bR0, aR[0][0], 0, 0, 0);
            aR[0][1] = __builtin_amdgcn_mfma_f32_16x16x32_f16(a0, bR1, aR[0][1], 0, 0, 0);
            aR[1][0] = __builtin_amdgcn_mfma_f32_16x16x32_f16(a1, bR0, aR[1][0], 0, 0, 0);
            aR[1][1] = __builtin_amdgcn_mfma_f32_16x16x32_f16(a1, bR1, aR[1][1], 0, 0, 0);
            half8 bZ0 = ldB(prep + WHH_OFF, 48, 16 + ntg0,     ks, whh, HID, use_prep, lane);
            half8 bZ1 = ldB(prep + WHH_OFF, 48, 16 + ntg0 + 1, ks, whh, HID, use_prep, lane);
            aZ[0][0] = __builtin_amdgcn_mfma_f32_16x16x32_f16(a0, bZ0, aZ[0][0], 0, 0, 0);
            aZ[0][1] = __builtin_amdgcn_mfma_f32_16x16x32_f16(a0, bZ1, aZ[0][1], 0, 0, 0);
            aZ[1][0] = __builtin_amdgcn_mfma_f32_16x16x32_f16(a1, bZ0, aZ[1][0], 0, 0, 0);
            aZ[1][1] = __builtin_amdgcn_mfma_f32_16x16x32_f16(a1, bZ1, aZ[1][1], 0, 0, 0);
            half8 bN0 = ldB(prep + WHH_OFF, 48, 32 + ntg0,     ks, whh, HID, use_prep, lane);
            half8 bN1 = ldB(prep + WHH_OFF, 48, 32 + ntg0 + 1, ks, whh, HID, use_prep, lane);
            aN[0][0] = __builtin_amdgcn_mfma_f32_16x16x32_f16(a0, bN0, aN[0][0], 0, 0, 0);
            aN[0][1] = __builtin_amdgcn_mfma_f32_16x16x32_f16(a0, bN1, aN[0][1], 0, 0, 0);
            aN[1][0] = __builtin_amdgcn_mfma_f32_16x16x32_f16(a1, bN0, aN[1][0], 0, 0, 0);
            aN[1][1] = __builtin_amdgcn_mfma_f32_16x16x32_f16(a1, bN1, aN[1][1], 0, 0, 0);
        }
        #pragma unroll
        for (int nt = 0; nt < 2; nt++) {
            int col = wc * 32 + nt * 16 + l16;
            float biR = b_ih[col],       bhR = b_hh[col];
            float biZ = b_ih[256 + col], bhZ = b_hh[256 + col];
            float biN = b_ih[512 + col], bhN = b_hh[512 + col];
            float psum = 0.f;
            #pragma unroll
            for (int mt = 0; mt < 2; mt++)
                #pragma unroll
                for (int r = 0; r < 4; r++) {
                    int row = rowB + mt * 16 + quad * 4 + r;
                    float rg = sigmoid_f(biR + aR[mt][nt][r] + bhR);
                    float zg = sigmoid_f(biZ + aZ[mt][nt][r] + bhZ);
                    float ng = tanh_f(biN + rg * (aN[mt][nt][r] + bhN));
                    float hold = (float)sA[0][row * SA + col];
                    float h1 = (1.f - zg) * ng + zg * hold;
                    sA[1][row * SA + col] = (_Float16)h1;   // h1 -> T1
                    psum += h1;
                }
            // sum over this wave's 32 rows (all in batch wr): reduce over quads
            psum += __shfl_xor(psum, 16);
            psum += __shfl_xor(psum, 32);
            if (lane < 16) S[wr][wc * 32 + nt * 16 + lane] = psum;
        }
    }
    __syncthreads();

    // ---- comm: c = (colsum - h1)/32 : T1 -> T0 (per-batch colsum), vectorized half8
    {
        #pragma unroll
        for (int it = 0; it < 2; it++) {
            int i  = tid + it * 1024;       // 2048 chunks total
            int r  = i >> 5;                // row 0..63
            int c8 = (i & 31) << 3;
            const float* Sp = &S[r >> 5][0];
            half8 hv = *(const half8*)(&sA[1][r * SA + c8]);
            float4v t0 = *(const float4v*)(Sp + c8);
            float4v t1 = *(const float4v*)(Sp + c8 + 4);
            half8 cv;
            cv[0] = (_Float16)((t0[0] - (float)hv[0]) * (1.f / 32.f));
            cv[1] = (_Float16)((t0[1] - (float)hv[1]) * (1.f / 32.f));
            cv[2] = (_Float16)((t0[2] - (float)hv[2]) * (1.f / 32.f));
            cv[3] = (_Float16)((t0[3] - (float)hv[3]) * (1.f / 32.f));
            cv[4] = (_Float16)((t1[0] - (float)hv[4]) * (1.f / 32.f));
            cv[5] = (_Float16)((t1[1] - (float)hv[5]) * (1.f / 32.f));
            cv[6] = (_Float16)((t1[2] - (float)hv[6]) * (1.f / 32.f));
            cv[7] = (_Float16)((t1[3] - (float)hv[7]) * (1.f / 32.f));
            *(half8*)(&sA[0][r * SA + c8]) = cv;
        }
        if (tid < MROWS) Srow[tid] = 0.f;   // decoder row accumulators
    }
    __syncthreads();

    // ---- GRU2 fused: gi from c (T0) @ W_ih, gh from h1 (T1) @ W_hh.
    // r,z gates share accumulators (sigmoid of gi+gh); n needs both halves.
    {
        float4v aR[2][2], aZ[2][2], aNi[2][2], aNh[2][2];
        zero22(aR); zero22(aZ); zero22(aNi); zero22(aNh);
        #pragma unroll 1
        for (int ks = 0; ks < 8; ks++) {
            const int kbase = ks * 32 + kq;
            // gi side: A = c
            {
                half8 c0 = *(const half8*)(&sA[0][(rowB + l16) * SA + kbase]);
                half8 c1 = *(const half8*)(&sA[0][(rowB + 16 + l16) * SA + kbase]);
                half8 bR0 = ldB(prep + WIH_OFF, 48,  0 + ntg0,     ks, wih, HID, use_prep, lane);
                half8 bR1 = ldB(prep + WIH_OFF, 48,  0 + ntg0 + 1, ks, wih, HID, use_prep, lane);
                aR[0][0]  = __builtin_amdgcn_mfma_f32_16x16x32_f16(c0, bR0, aR[0][0], 0, 0, 0);
                aR[0][1]  = __builtin_amdgcn_mfma_f32_16x16x32_f16(c0, bR1, aR[0][1], 0, 0, 0);
                aR[1][0]  = __builtin_amdgcn_mfma_f32_16x16x32_f16(c1, bR0, aR[1][0], 0, 0, 0);
                aR[1][1]  = __builtin_amdgcn_mfma_f32_16x16x32_f16(c1, bR1, aR[1][1], 0, 0, 0);
                half8 bZ0 = ldB(prep + WIH_OFF, 48, 16 + ntg0,     ks, wih, HID, use_prep, lane);
                half8 bZ1 = ldB(prep + WIH_OFF, 48, 16 + ntg0 + 1, ks, wih, HID, use_prep, lane);
                aZ[0][0]  = __builtin_amdgcn_mfma_f32_16x16x32_f16(c0, bZ0, aZ[0][0], 0, 0, 0);
                aZ[0][1]  = __builtin_amdgcn_mfma_f32_16x16x32_f16(c0, bZ1, aZ[0][1], 0, 0, 0);
                aZ[1][0]  = __builtin_amdgcn_mfma_f32_16x16x32_f16(c1, bZ0, aZ[1][0], 0, 0, 0);
                aZ[1][1]  = __builtin_amdgcn_mfma_f32_16x16x32_f16(c1, bZ1, aZ[1][1], 0, 0, 0);
                half8 bN0 = ldB(prep + WIH_OFF, 48, 32 + ntg0,     ks, wih, HID, use_prep, lane);
                half8 bN1 = ldB(prep + WIH_OFF, 48, 32 + ntg0 + 1, ks, wih, HID, use_prep, lane);
                aNi[0][0] = __builtin_amdgcn_mfma_f32_16x16x32_f16(c0, bN0, aNi[0][0], 0, 0, 0);
                aNi[0][1] = __builtin_amdgcn_mfma_f32_16x16x32_f16(c0, bN1, aNi[0][1], 0, 0, 0);
                aNi[1][0] = __builtin_amdgcn_mfma_f32_16x16x32_f16(c1, bN0, aNi[1][0], 0, 0, 0);
                aNi[1][1] = __builtin_amdgcn_mfma_f32_16x16x32_f16(c1, bN1, aNi[1][1], 0, 0, 0);
            }
            // gh side: A = h1
            {
                half8 h0 = *(const half8*)(&sA[1][(rowB + l16) * SA + kbase]);
                half8 h1f = *(const half8*)(&sA[1][(rowB + 16 + l16) * SA + kbase]);
                half8 bR0 = ldB(prep + WHH_OFF, 48,  0 + ntg0,     ks, whh, HID, use_prep, lane);
                half8 bR1 = ldB(prep + WHH_OFF, 48,  0 + ntg0 + 1, ks, whh, HID, use_prep, lane);
                aR[0][0]  = __builtin_amdgcn_mfma_f32_16x16x32_f16(h0,  bR0, aR[0][0], 0, 0, 0);
                aR[0][1]  = __builtin_amdgcn_mfma_f32_16x16x32_f16(h0,  bR1, aR[0][1], 0, 0, 0);
                aR[1][0]  = __builtin_amdgcn_mfma_f32_16x16x32_f16(h1f, bR0, aR[1][0], 0, 0, 0);
                aR[1][1]  = __builtin_amdgcn_mfma_f32_16x16x32_f16(h1f, bR1, aR[1][1], 0, 0, 0);
                half8 bZ0 = ldB(prep + WHH_OFF, 48, 16 + ntg0,     ks, whh, HID, use_prep, lane);
                half8 bZ1 = ldB(prep + WHH_OFF, 48, 16 + ntg0 + 1, ks, whh, HID, use_prep, lane);
                aZ[0][0]  = __builtin_amdgcn_mfma_f32_16x16x32_f16(h0,  bZ0, aZ[0][0], 0, 0, 0);
                aZ[0][1]  = __builtin_amdgcn_mfma_f32_16x16x32_f16(h0,  bZ1, aZ[0][1], 0, 0, 0);
                aZ[1][0]  = __builtin_amdgcn_mfma_f32_16x16x32_f16(h1f, bZ0, aZ[1][0], 0, 0, 0);
                aZ[1][1]  = __builtin_amdgcn_mfma_f32_16x16x32_f16(h1f, bZ1, aZ[1][1], 0, 0, 0);
                half8 bN0 = ldB(prep + WHH_OFF, 48, 32 + ntg0,     ks, whh, HID, use_prep, lane);
                half8 bN1 = ldB(prep + WHH_OFF, 48, 32 + ntg0 + 1, ks, whh, HID, use_prep, lane);
                aNh[0][0] = __builtin_amdgcn_mfma_f32_16x16x32_f16(h0,  bN0, aNh[0][0], 0, 0, 0);
                aNh[0][1] = __builtin_amdgcn_mfma_f32_16x16x32_f16(h0,  bN1, aNh[0][1], 0, 0, 0);
                aNh[1][0] = __builtin_amdgcn_mfma_f32_16x16x32_f16(h1f, bN0, aNh[1][0], 0, 0, 0);
                aNh[1][1] = __builtin_amdgcn_mfma_f32_16x16x32_f16(h1f, bN1, aNh[1][1], 0, 0, 0);
            }
        }

        // ---- epilogue + decoder fold: out[row] = sum_col h2*dec_W[col] + dec_b
        float p[2][4];
        #pragma unroll
        for (int mt = 0; mt < 2; mt++)
            #pragma unroll
            for (int r = 0; r < 4; r++)
                p[mt][r] = 0.f;
        #pragma unroll
        for (int nt = 0; nt < 2; nt++) {
            int col = wc * 32 + nt * 16 + l16;
            float biR = b_ih[col],       bhR = b_hh[col];
            float biZ = b_ih[256 + col], bhZ = b_hh[256 + col];
            float biN = b_ih[512 + col], bhN = b_hh[512 + col];
            float dw  = dec_W[col];
            #pragma unroll
            for (int mt = 0; mt < 2; mt++)
                #pragma unroll
                for (int r = 0; r < 4; r++) {
                    int row = rowB + mt * 16 + quad * 4 + r;
                    float rg = sigmoid_f(aR[mt][nt][r] + biR + bhR);
                    float zg = sigmoid_f(aZ[mt][nt][r] + biZ + bhZ);
                    float ng = tanh_f((aNi[mt][nt][r] + biN) + rg * (aNh[mt][nt][r] + bhN));
                    float h1v = (float)sA[1][row * SA + col];
                    float h2 = (1.f - zg) * ng + zg * h1v;
                    p[mt][r] += h2 * dw;
                }
        }
        #pragma unroll
        for (int m = 1; m <= 8; m <<= 1) {
            #pragma unroll
            for (int mt = 0; mt < 2; mt++)
                #pragma unroll
                for (int r = 0; r < 4; r++)
                    p[mt][r] += __shfl_xor(p[mt][r], m);
        }
        if (l16 == 0) {
            #pragma unroll
            for (int mt = 0; mt < 2; mt++)
                #pragma unroll
                for (int r = 0; r < 4; r++)
                    atomicAdd(&Srow[rowB + mt * 16 + quad * 4 + r], p[mt][r]);
        }
    }
    __syncthreads();
    if (tid < MROWS) out[(size_t)b * MROWS + tid] = Srow[tid] + dec_b[0];
}

extern "C" void kernel_launch(void* const* d_in, const int* in_sizes, int n_in,
                              void* d_out, int out_size, void* d_ws, size_t ws_size,
                              hipStream_t stream) {
    const float* obs   = (const float*)d_in[0];
    // d_in[1] (act) is unused by the reference
    const float* encW  = (const float*)d_in[2];
    const float* encb  = (const float*)d_in[3];
    const float* fobsW = (const float*)d_in[4];
    const float* fobsb = (const float*)d_in[5];
    const float* wih   = (const float*)d_in[6];
    const float* bih   = (const float*)d_in[7];
    const float* whh   = (const float*)d_in[8];
    const float* bhh   = (const float*)d_in[9];
    const float* decW  = (const float*)d_in[10];
    const float* decb  = (const float*)d_in[11];
    float* out = (float*)d_out;

    _Float16* prep = (_Float16*)d_ws;
    int use_prep = (ws_size >= (size_t)PREP_TOTAL * sizeof(_Float16)) ? 1 : 0;
    if (use_prep) {
        prep_weights<<<(PREP_TOTAL + 255) / 256, 256, 0, stream>>>(encW, fobsW, wih, whh, prep);
    }
    commnet_fused<<<NB / 2, 1024, 0, stream>>>(obs, prep, encb, fobsb, bih, bhh, decW, decb, out,
                                               encW, fobsW, wih, whh, use_prep);
}

// Round 7
// 236.407 us; speedup vs baseline: 1.3713x; 1.3713x over previous
//
#include <hip/hip_runtime.h>
#include <hip/hip_fp16.h>

// CommNet critic forward, fully fused: 1 workgroup = 2 batches (64 agent-rows).
// All GEMMs via v_mfma_f32_16x16x32_f16 (fp32 accumulate). B=2048,A=32,D=128,H=256.
// V8: V3 structure at 512 threads/block. Empirically the allocator gives 1024-thread
//     blocks 64 VGPRs (V3..V7, all knobs failed) -> GRU accs spill (~115MB scratch);
//     512-thread blocks get ~108 VGPRs spill-free (V2: WRITE_SIZE=0.25MB).
//     8 waves x (64 rows x 16 cols) tiles, TWO sequential col-tile passes per phase:
//     per-block ds_read/B-load/MFMA totals identical to V3's 16-wave version.

#define NB   2048
#define NA   32
#define DIN  128
#define HID  256
#define SA   264   // f16 row stride for activation LDS tiles (528B stride -> 4-bank stagger)
#define MROWS 64   // 2 batches x 32 agents

typedef _Float16 half8  __attribute__((ext_vector_type(8)));
typedef float    float4v __attribute__((ext_vector_type(4)));

// f16 weight-fragment arena layout in d_ws (element offsets)
#define ENC_OFF    0
#define FOBS_OFF   32768
#define WIH_OFF    98304
#define WHH_OFF    294912
#define PREP_TOTAL 491520   // f16 elements -> 983040 bytes needed in ws

// Pre-arrange weights into exact MFMA B-fragment order, f16:
// frag[((ks*NT + nt)*64 + lane)*8 + j] = W[nt*16 + lane%16][ks*32 + (lane/16)*8 + j]
__global__ void prep_weights(const float* __restrict__ encW, const float* __restrict__ fobsW,
                             const float* __restrict__ wih,  const float* __restrict__ whh,
                             _Float16* __restrict__ prep) {
    int F = blockIdx.x * 256 + threadIdx.x;
    if (F >= PREP_TOTAL) return;
    const float* src; int K, NT, local = F;
    if (F < FOBS_OFF)     { src = encW;  K = 128; NT = 16; }
    else if (F < WIH_OFF) { src = fobsW; K = 256; NT = 16; local = F - FOBS_OFF; }
    else if (F < WHH_OFF) { src = wih;   K = 256; NT = 48; local = F - WIH_OFF; }
    else                  { src = whh;   K = 256; NT = 48; local = F - WHH_OFF; }
    int j    = local & 7;
    int lane = (local >> 3) & 63;
    int t    = local >> 9;
    int nt   = t % NT;
    int ks   = t / NT;
    int col  = nt * 16 + (lane & 15);
    int k    = ks * 32 + ((lane >> 4) << 3) + j;
    prep[F] = (_Float16)src[col * K + k];
}

__device__ __forceinline__ float sigmoid_f(float x) {
    x = fminf(fmaxf(x, -30.f), 30.f);
    return 1.f / (1.f + __expf(-x));
}
__device__ __forceinline__ float tanh_f(float x) {
    x = fminf(fmaxf(x, -15.f), 15.f);
    float e = __expf(-2.f * x);
    return (1.f - e) / (1.f + e);
}

// Load one MFMA B-fragment (16 cols x 32 k) either from prepped arena or raw fp32.
__device__ __forceinline__ half8 ldB(const _Float16* __restrict__ prepm, int NT, int nt, int ks,
                                     const float* __restrict__ raw, int K, int use_prep, int lane) {
    if (use_prep)
        return *(const half8*)(prepm + (((ks * NT + nt) * 64 + lane) << 3));
    half8 b;
    int l16 = lane & 15, kq = (lane >> 4) << 3;
    #pragma unroll
    for (int j = 0; j < 8; j++)
        b[j] = (_Float16)raw[(nt * 16 + l16) * K + ks * 32 + kq + j];
    return b;
}

__global__ __launch_bounds__(512) void commnet_fused(
    const float* __restrict__ obs, const _Float16* __restrict__ prep,
    const float* __restrict__ enc_b, const float* __restrict__ fobs_b,
    const float* __restrict__ b_ih, const float* __restrict__ b_hh,
    const float* __restrict__ dec_W, const float* __restrict__ dec_b,
    float* __restrict__ out,
    const float* __restrict__ encW, const float* __restrict__ fobsW,
    const float* __restrict__ wih, const float* __restrict__ whh,
    int use_prep)
{
    const int b    = blockIdx.x;       // block handles batches 2b, 2b+1 (rows 0..63)
    const int tid  = threadIdx.x;
    const int lane = tid & 63;
    const int w    = tid >> 6;         // wave 0..7; owns col tiles 2w and 2w+1
    const int l16  = lane & 15;
    const int quad = lane >> 4;
    const int kq   = quad << 3;
    const int nt0  = w * 2;

    __shared__ __align__(16) _Float16 sA[2][MROWS * SA];
    __shared__ __align__(16) float S[2][HID];   // per-batch column sums of h1
    __shared__ float Srow[MROWS];               // decoder row accumulators

    // ---- stage obs (fp32 global -> f16 LDS): 64 rows x 128, 2 half8 per thread
    {
        const float* obsb = obs + (size_t)b * MROWS * DIN;
        #pragma unroll
        for (int it = 0; it < 2; it++) {
            int i   = tid + it * 512;      // 1024 chunks
            int r   = i >> 4;
            int off = (i & 15) << 3;
            const float* src = obsb + r * DIN + off;
            float4v v0 = *(const float4v*)(src);
            float4v v1 = *(const float4v*)(src + 4);
            half8 hv;
            hv[0] = (_Float16)v0[0]; hv[1] = (_Float16)v0[1];
            hv[2] = (_Float16)v0[2]; hv[3] = (_Float16)v0[3];
            hv[4] = (_Float16)v1[0]; hv[5] = (_Float16)v1[1];
            hv[6] = (_Float16)v1[2]; hv[7] = (_Float16)v1[3];
            *(half8*)(&sA[0][r * SA + off]) = hv;
        }
    }
    __syncthreads();

    // ---- encoder: e = relu(obs @ encW^T + enc_b) : T0 -> T1 (both tiles at once)
    {
        float4v acc[4][2];
        float4v z = {0.f, 0.f, 0.f, 0.f};
        #pragma unroll
        for (int mt = 0; mt < 4; mt++) { acc[mt][0] = z; acc[mt][1] = z; }
        #pragma unroll
        for (int ks = 0; ks < 4; ks++) {
            int kbase = ks * 32 + kq;
            half8 Af[4];
            #pragma unroll
            for (int mt = 0; mt < 4; mt++)
                Af[mt] = *(const half8*)(&sA[0][(mt * 16 + l16) * SA + kbase]);
            half8 b0 = ldB(prep + ENC_OFF, 16, nt0,     ks, encW, DIN, use_prep, lane);
            half8 b1 = ldB(prep + ENC_OFF, 16, nt0 + 1, ks, encW, DIN, use_prep, lane);
            #pragma unroll
            for (int mt = 0; mt < 4; mt++) {
                acc[mt][0] = __builtin_amdgcn_mfma_f32_16x16x32_f16(Af[mt], b0, acc[mt][0], 0, 0, 0);
                acc[mt][1] = __builtin_amdgcn_mfma_f32_16x16x32_f16(Af[mt], b1, acc[mt][1], 0, 0, 0);
            }
        }
        #pragma unroll
        for (int nt = 0; nt < 2; nt++) {
            int col = (nt0 + nt) * 16 + l16;
            float bb = enc_b[col];
            #pragma unroll
            for (int mt = 0; mt < 4; mt++)
                #pragma unroll
                for (int r = 0; r < 4; r++) {
                    int row = mt * 16 + quad * 4 + r;
                    sA[1][row * SA + col] = (_Float16)fmaxf(acc[mt][nt][r] + bb, 0.f);
                }
        }
    }
    __syncthreads();

    // ---- fobs: h = e @ fobsW^T + fobs_b : T1 -> T0 (both tiles at once)
    {
        float4v acc[4][2];
        float4v z = {0.f, 0.f, 0.f, 0.f};
        #pragma unroll
        for (int mt = 0; mt < 4; mt++) { acc[mt][0] = z; acc[mt][1] = z; }
        #pragma unroll 2
        for (int ks = 0; ks < 8; ks++) {
            int kbase = ks * 32 + kq;
            half8 Af[4];
            #pragma unroll
            for (int mt = 0; mt < 4; mt++)
                Af[mt] = *(const half8*)(&sA[1][(mt * 16 + l16) * SA + kbase]);
            half8 b0 = ldB(prep + FOBS_OFF, 16, nt0,     ks, fobsW, HID, use_prep, lane);
            half8 b1 = ldB(prep + FOBS_OFF, 16, nt0 + 1, ks, fobsW, HID, use_prep, lane);
            #pragma unroll
            for (int mt = 0; mt < 4; mt++) {
                acc[mt][0] = __builtin_amdgcn_mfma_f32_16x16x32_f16(Af[mt], b0, acc[mt][0], 0, 0, 0);
                acc[mt][1] = __builtin_amdgcn_mfma_f32_16x16x32_f16(Af[mt], b1, acc[mt][1], 0, 0, 0);
            }
        }
        #pragma unroll
        for (int nt = 0; nt < 2; nt++) {
            int col = (nt0 + nt) * 16 + l16;
            float bb = fobs_b[col];
            #pragma unroll
            for (int mt = 0; mt < 4; mt++)
                #pragma unroll
                for (int r = 0; r < 4; r++) {
                    int row = mt * 16 + quad * 4 + r;
                    sA[0][row * SA + col] = (_Float16)(acc[mt][nt][r] + bb);
                }
        }
    }
    __syncthreads();

    // ---- GRU1 fused (x=0 so gi = b_ih). A = T0 (h). Two sequential col-tile passes.
    #pragma unroll 1
    for (int ps = 0; ps < 2; ps++) {
        const int nt = nt0 + ps;
        float4v aR[4], aZ[4], aN[4];
        float4v z = {0.f, 0.f, 0.f, 0.f};
        #pragma unroll
        for (int mt = 0; mt < 4; mt++) { aR[mt] = z; aZ[mt] = z; aN[mt] = z; }
        #pragma unroll 2
        for (int ks = 0; ks < 8; ks++) {
            const int kbase = ks * 32 + kq;
            half8 Af[4];
            #pragma unroll
            for (int mt = 0; mt < 4; mt++)
                Af[mt] = *(const half8*)(&sA[0][(mt * 16 + l16) * SA + kbase]);
            half8 bR = ldB(prep + WHH_OFF, 48,  0 + nt, ks, whh, HID, use_prep, lane);
            half8 bZ = ldB(prep + WHH_OFF, 48, 16 + nt, ks, whh, HID, use_prep, lane);
            half8 bN = ldB(prep + WHH_OFF, 48, 32 + nt, ks, whh, HID, use_prep, lane);
            #pragma unroll
            for (int mt = 0; mt < 4; mt++)
                aR[mt] = __builtin_amdgcn_mfma_f32_16x16x32_f16(Af[mt], bR, aR[mt], 0, 0, 0);
            #pragma unroll
            for (int mt = 0; mt < 4; mt++)
                aZ[mt] = __builtin_amdgcn_mfma_f32_16x16x32_f16(Af[mt], bZ, aZ[mt], 0, 0, 0);
            #pragma unroll
            for (int mt = 0; mt < 4; mt++)
                aN[mt] = __builtin_amdgcn_mfma_f32_16x16x32_f16(Af[mt], bN, aN[mt], 0, 0, 0);
        }
        int col = nt * 16 + l16;
        float biR = b_ih[col],       bhR = b_hh[col];
        float biZ = b_ih[256 + col], bhZ = b_hh[256 + col];
        float biN = b_ih[512 + col], bhN = b_hh[512 + col];
        float s0 = 0.f, s1 = 0.f;
        #pragma unroll
        for (int mt = 0; mt < 4; mt++) {
            float psum = 0.f;
            #pragma unroll
            for (int r = 0; r < 4; r++) {
                int row = mt * 16 + quad * 4 + r;
                float rg = sigmoid_f(biR + aR[mt][r] + bhR);
                float zg = sigmoid_f(biZ + aZ[mt][r] + bhZ);
                float ng = tanh_f(biN + rg * (aN[mt][r] + bhN));
                float hold = (float)sA[0][row * SA + col];
                float h1 = (1.f - zg) * ng + zg * hold;
                sA[1][row * SA + col] = (_Float16)h1;   // h1 -> T1
                psum += h1;
            }
            if (mt < 2) s0 += psum; else s1 += psum;
        }
        // column sums across the 4 quads (rows within each batch) -> S, no atomics
        s0 += __shfl_xor(s0, 16); s0 += __shfl_xor(s0, 32);
        s1 += __shfl_xor(s1, 16); s1 += __shfl_xor(s1, 32);
        if (lane < 16) { S[0][nt * 16 + lane] = s0; S[1][nt * 16 + lane] = s1; }
    }
    __syncthreads();

    // ---- comm: c = (colsum - h1)/32 : T1 -> T0 (per-batch colsum), vectorized half8
    {
        #pragma unroll
        for (int it = 0; it < 4; it++) {
            int i  = tid + it * 512;        // 2048 chunks total
            int r  = i >> 5;                // row 0..63
            int c8 = (i & 31) << 3;
            const float* Sp = &S[r >> 5][0];
            half8 hv = *(const half8*)(&sA[1][r * SA + c8]);
            float4v t0 = *(const float4v*)(Sp + c8);
            float4v t1 = *(const float4v*)(Sp + c8 + 4);
            half8 cv;
            cv[0] = (_Float16)((t0[0] - (float)hv[0]) * (1.f / 32.f));
            cv[1] = (_Float16)((t0[1] - (float)hv[1]) * (1.f / 32.f));
            cv[2] = (_Float16)((t0[2] - (float)hv[2]) * (1.f / 32.f));
            cv[3] = (_Float16)((t0[3] - (float)hv[3]) * (1.f / 32.f));
            cv[4] = (_Float16)((t1[0] - (float)hv[4]) * (1.f / 32.f));
            cv[5] = (_Float16)((t1[1] - (float)hv[5]) * (1.f / 32.f));
            cv[6] = (_Float16)((t1[2] - (float)hv[6]) * (1.f / 32.f));
            cv[7] = (_Float16)((t1[3] - (float)hv[7]) * (1.f / 32.f));
            *(half8*)(&sA[0][r * SA + c8]) = cv;
        }
        if (tid < MROWS) Srow[tid] = 0.f;   // decoder row accumulators
    }
    __syncthreads();

    // ---- GRU2 fused: gi from c (T0) @ W_ih, gh from h1 (T1) @ W_hh.
    // Two sequential col-tile passes; decoder fold reduced inside each pass.
    #pragma unroll 1
    for (int ps = 0; ps < 2; ps++) {
        const int nt = nt0 + ps;
        float4v aR[4], aZ[4], aNi[4], aNh[4];
        float4v z = {0.f, 0.f, 0.f, 0.f};
        #pragma unroll
        for (int mt = 0; mt < 4; mt++) { aR[mt] = z; aZ[mt] = z; aNi[mt] = z; aNh[mt] = z; }
        #pragma unroll 1
        for (int ks = 0; ks < 8; ks++) {
            const int kbase = ks * 32 + kq;
            // gi side: A = c
            {
                half8 Cf[4];
                #pragma unroll
                for (int mt = 0; mt < 4; mt++)
                    Cf[mt] = *(const half8*)(&sA[0][(mt * 16 + l16) * SA + kbase]);
                half8 bR = ldB(prep + WIH_OFF, 48,  0 + nt, ks, wih, HID, use_prep, lane);
                half8 bZ = ldB(prep + WIH_OFF, 48, 16 + nt, ks, wih, HID, use_prep, lane);
                half8 bN = ldB(prep + WIH_OFF, 48, 32 + nt, ks, wih, HID, use_prep, lane);
                #pragma unroll
                for (int mt = 0; mt < 4; mt++)
                    aR[mt]  = __builtin_amdgcn_mfma_f32_16x16x32_f16(Cf[mt], bR, aR[mt], 0, 0, 0);
                #pragma unroll
                for (int mt = 0; mt < 4; mt++)
                    aZ[mt]  = __builtin_amdgcn_mfma_f32_16x16x32_f16(Cf[mt], bZ, aZ[mt], 0, 0, 0);
                #pragma unroll
                for (int mt = 0; mt < 4; mt++)
                    aNi[mt] = __builtin_amdgcn_mfma_f32_16x16x32_f16(Cf[mt], bN, aNi[mt], 0, 0, 0);
            }
            // gh side: A = h1
            {
                half8 Hf[4];
                #pragma unroll
                for (int mt = 0; mt < 4; mt++)
                    Hf[mt] = *(const half8*)(&sA[1][(mt * 16 + l16) * SA + kbase]);
                half8 bR = ldB(prep + WHH_OFF, 48,  0 + nt, ks, whh, HID, use_prep, lane);
                half8 bZ = ldB(prep + WHH_OFF, 48, 16 + nt, ks, whh, HID, use_prep, lane);
                half8 bN = ldB(prep + WHH_OFF, 48, 32 + nt, ks, whh, HID, use_prep, lane);
                #pragma unroll
                for (int mt = 0; mt < 4; mt++)
                    aR[mt]  = __builtin_amdgcn_mfma_f32_16x16x32_f16(Hf[mt], bR, aR[mt], 0, 0, 0);
                #pragma unroll
                for (int mt = 0; mt < 4; mt++)
                    aZ[mt]  = __builtin_amdgcn_mfma_f32_16x16x32_f16(Hf[mt], bZ, aZ[mt], 0, 0, 0);
                #pragma unroll
                for (int mt = 0; mt < 4; mt++)
                    aNh[mt] = __builtin_amdgcn_mfma_f32_16x16x32_f16(Hf[mt], bN, aNh[mt], 0, 0, 0);
            }
        }

        // epilogue + decoder fold for this tile
        int col = nt * 16 + l16;
        float biR = b_ih[col],       bhR = b_hh[col];
        float biZ = b_ih[256 + col], bhZ = b_hh[256 + col];
        float biN = b_ih[512 + col], bhN = b_hh[512 + col];
        float dw  = dec_W[col];
        float p[4][4];
        #pragma unroll
        for (int mt = 0; mt < 4; mt++)
            #pragma unroll
            for (int r = 0; r < 4; r++) {
                int row = mt * 16 + quad * 4 + r;
                float rg = sigmoid_f(aR[mt][r] + biR + bhR);
                float zg = sigmoid_f(aZ[mt][r] + biZ + bhZ);
                float ng = tanh_f((aNi[mt][r] + biN) + rg * (aNh[mt][r] + bhN));
                float h1v = (float)sA[1][row * SA + col];
                float h2 = (1.f - zg) * ng + zg * h1v;
                p[mt][r] = h2 * dw;
            }
        #pragma unroll
        for (int m = 1; m <= 8; m <<= 1) {
            #pragma unroll
            for (int mt = 0; mt < 4; mt++)
                #pragma unroll
                for (int r = 0; r < 4; r++)
                    p[mt][r] += __shfl_xor(p[mt][r], m);
        }
        if (l16 == 0) {
            #pragma unroll
            for (int mt = 0; mt < 4; mt++)
                #pragma unroll
                for (int r = 0; r < 4; r++)
                    atomicAdd(&Srow[mt * 16 + quad * 4 + r], p[mt][r]);
        }
    }
    __syncthreads();
    if (tid < MROWS) out[(size_t)b * MROWS + tid] = Srow[tid] + dec_b[0];
}

extern "C" void kernel_launch(void* const* d_in, const int* in_sizes, int n_in,
                              void* d_out, int out_size, void* d_ws, size_t ws_size,
                              hipStream_t stream) {
    const float* obs   = (const float*)d_in[0];
    // d_in[1] (act) is unused by the reference
    const float* encW  = (const float*)d_in[2];
    const float* encb  = (const float*)d_in[3];
    const float* fobsW = (const float*)d_in[4];
    const float* fobsb = (const float*)d_in[5];
    const float* wih   = (const float*)d_in[6];
    const float* bih   = (const float*)d_in[7];
    const float* whh   = (const float*)d_in[8];
    const float* bhh   = (const float*)d_in[9];
    const float* decW  = (const float*)d_in[10];
    const float* decb  = (const float*)d_in[11];
    float* out = (float*)d_out;

    _Float16* prep = (_Float16*)d_ws;
    int use_prep = (ws_size >= (size_t)PREP_TOTAL * sizeof(_Float16)) ? 1 : 0;
    if (use_prep) {
        prep_weights<<<(PREP_TOTAL + 255) / 256, 256, 0, stream>>>(encW, fobsW, wih, whh, prep);
    }
    commnet_fused<<<NB / 2, 512, 0, stream>>>(obs, prep, encb, fobsb, bih, bhh, decW, decb, out,
                                              encW, fobsW, wih, whh, use_prep);
}